// Round 1
// baseline (356.026 us; speedup 1.0000x reference)
//
#include <hip/hip_runtime.h>

// DenselyCnnAttLayer: B=64, S=512, L=6, D=512, fp32.
// One wave per (b,s) position. Memory-bound: ~470 MiB total traffic.
constexpr int Bc = 64, Sc = 512, Lc = 6, Dc = 512;

__global__ __launch_bounds__(256) void densely_att_kernel(
    const float* __restrict__ x0, const float* __restrict__ x1,
    const float* __restrict__ x2, const float* __restrict__ x3,
    const float* __restrict__ x4, const float* __restrict__ x5,
    const float* __restrict__ Ws, float* __restrict__ out)
{
    const int wave = threadIdx.x >> 6;   // 4 waves per block
    const int lane = threadIdx.x & 63;
    const long pos = (long)blockIdx.x * 4 + wave;   // pos = b*S + s, in [0, B*S)

    // seq index for Ws lookup; wave-uniform -> force scalar
    const int s_idx = __builtin_amdgcn_readfirstlane((int)(pos % Sc));

    const float* xs[Lc] = {x0, x1, x2, x3, x4, x5};

    // Lane i covers d = 4*i .. 4*i+3  and  d = 256 + 4*i .. 256+4*i+3
    const size_t base0 = (size_t)pos * Dc + (size_t)lane * 4;
    const size_t base1 = base0 + 256;

    float4 v[Lc][2];
    float ssum[Lc];
    #pragma unroll
    for (int j = 0; j < Lc; ++j) {
        v[j][0] = *(const float4*)(xs[j] + base0);
        v[j][1] = *(const float4*)(xs[j] + base1);
        ssum[j] = (v[j][0].x + v[j][0].y) + (v[j][0].z + v[j][0].w)
                + (v[j][1].x + v[j][1].y) + (v[j][1].z + v[j][1].w);
    }

    // Butterfly reduce across the 64-lane wave: every lane ends with full sum over D.
    #pragma unroll
    for (int off = 32; off >= 1; off >>= 1) {
        #pragma unroll
        for (int j = 0; j < Lc; ++j)
            ssum[j] += __shfl_xor(ssum[j], off, 64);
    }

    // logits[m] = sum_l ssum[l] * Ws[s, l, m];  Ws is (S, L, L) row-major
    const float* __restrict__ w = Ws + (size_t)s_idx * (Lc * Lc);
    float logits[Lc];
    #pragma unroll
    for (int m = 0; m < Lc; ++m) {
        float acc = 0.f;
        #pragma unroll
        for (int l = 0; l < Lc; ++l)
            acc = fmaf(ssum[l], w[l * Lc + m], acc);
        logits[m] = acc;
    }

    // softmax over L (redundant per lane; 6 elements, cheap)
    float mx = logits[0];
    #pragma unroll
    for (int m = 1; m < Lc; ++m) mx = fmaxf(mx, logits[m]);
    float a[Lc];
    float denom = 0.f;
    #pragma unroll
    for (int m = 0; m < Lc; ++m) {
        a[m] = __expf(logits[m] - mx);
        denom += a[m];
    }
    const float inv = 1.f / denom;
    #pragma unroll
    for (int m = 0; m < Lc; ++m) a[m] *= inv;

    // out[d] = sum_j a[j] * x_j[d]
    float4 o0 = make_float4(0.f, 0.f, 0.f, 0.f);
    float4 o1 = make_float4(0.f, 0.f, 0.f, 0.f);
    #pragma unroll
    for (int j = 0; j < Lc; ++j) {
        o0.x = fmaf(a[j], v[j][0].x, o0.x);
        o0.y = fmaf(a[j], v[j][0].y, o0.y);
        o0.z = fmaf(a[j], v[j][0].z, o0.z);
        o0.w = fmaf(a[j], v[j][0].w, o0.w);
        o1.x = fmaf(a[j], v[j][1].x, o1.x);
        o1.y = fmaf(a[j], v[j][1].y, o1.y);
        o1.z = fmaf(a[j], v[j][1].z, o1.z);
        o1.w = fmaf(a[j], v[j][1].w, o1.w);
    }
    *(float4*)(out + base0) = o0;
    *(float4*)(out + base1) = o1;
}

extern "C" void kernel_launch(void* const* d_in, const int* in_sizes, int n_in,
                              void* d_out, int out_size, void* d_ws, size_t ws_size,
                              hipStream_t stream) {
    const float* x0 = (const float*)d_in[0];
    const float* x1 = (const float*)d_in[1];
    const float* x2 = (const float*)d_in[2];
    const float* x3 = (const float*)d_in[3];
    const float* x4 = (const float*)d_in[4];
    const float* x5 = (const float*)d_in[5];
    const float* Ws = (const float*)d_in[6];
    float* out = (float*)d_out;

    const int positions = Bc * Sc;          // 32768
    const int blocks = positions / 4;       // 4 waves (positions) per block
    densely_att_kernel<<<blocks, 256, 0, stream>>>(x0, x1, x2, x3, x4, x5, Ws, out);
}

// Round 2
// 351.068 us; speedup vs baseline: 1.0141x; 1.0141x over previous
//
#include <hip/hip_runtime.h>

// DenselyCnnAttLayer: B=64, S=512, L=6, D=512, fp32.
// Two waves per (b,s) position (each covers 256 of D) so per-lane live
// x-data is 24 floats -> fits comfortably under 64 VGPRs (8 waves/SIMD at
// zero occupancy cost). R1 post-mortem: with 48 floats live the compiler
// rematerialized the global loads (VGPR_Count=32), doubling read traffic.
constexpr int Bc = 64, Sc = 512, Lc = 6, Dc = 512;

// Forbid load rematerialization: value becomes opaque to the optimizer.
#define KEEP4(v) asm volatile("" : "+v"((v).x), "+v"((v).y), "+v"((v).z), "+v"((v).w))

__global__ __launch_bounds__(256) void densely_att_kernel(
    const float* __restrict__ x0, const float* __restrict__ x1,
    const float* __restrict__ x2, const float* __restrict__ x3,
    const float* __restrict__ x4, const float* __restrict__ x5,
    const float* __restrict__ Ws, float* __restrict__ out)
{
    const int wave = threadIdx.x >> 6;     // 0..3
    const int lane = threadIdx.x & 63;
    const int pair = wave >> 1;            // 0..1 : which position in this block
    const int half = wave & 1;             // 0..1 : which half of D

    const long pos = (long)blockIdx.x * 2 + pair;        // b*S + s
    const int s_idx = __builtin_amdgcn_readfirstlane((int)(pos % Sc));

    const float* xs[Lc] = {x0, x1, x2, x3, x4, x5};

    // Each lane covers d = half*256 + lane*4 .. +3  (one float4 per array)
    const size_t base = (size_t)pos * Dc + (size_t)half * 256 + (size_t)lane * 4;

    float4 v[Lc];
    float ssum[Lc];
    #pragma unroll
    for (int j = 0; j < Lc; ++j) {
        v[j] = *(const float4*)(xs[j] + base);
        KEEP4(v[j]);
        ssum[j] = (v[j].x + v[j].y) + (v[j].z + v[j].w);
    }

    // Butterfly reduce across the 64-lane wave -> sum over this half of D.
    #pragma unroll
    for (int off = 32; off >= 1; off >>= 1) {
        #pragma unroll
        for (int j = 0; j < Lc; ++j)
            ssum[j] += __shfl_xor(ssum[j], off, 64);
    }

    // Combine the two half-sums through LDS (24 B per position).
    __shared__ float sums[2][2][Lc];
    if (lane == 0) {
        #pragma unroll
        for (int j = 0; j < Lc; ++j) sums[pair][half][j] = ssum[j];
    }
    __syncthreads();
    #pragma unroll
    for (int j = 0; j < Lc; ++j)
        ssum[j] = sums[pair][0][j] + sums[pair][1][j];

    // logits[m] = sum_l ssum[l] * Ws[s, l, m];  Ws is (S, L, L) row-major
    const float* __restrict__ w = Ws + (size_t)s_idx * (Lc * Lc);
    float logits[Lc];
    #pragma unroll
    for (int m = 0; m < Lc; ++m) {
        float acc = 0.f;
        #pragma unroll
        for (int l = 0; l < Lc; ++l)
            acc = fmaf(ssum[l], w[l * Lc + m], acc);
        logits[m] = acc;
    }

    // softmax over L (redundant per lane; 6 values, cheap)
    float mx = logits[0];
    #pragma unroll
    for (int m = 1; m < Lc; ++m) mx = fmaxf(mx, logits[m]);
    float a[Lc];
    float denom = 0.f;
    #pragma unroll
    for (int m = 0; m < Lc; ++m) {
        a[m] = __expf(logits[m] - mx);
        denom += a[m];
    }
    const float inv = 1.f / denom;
    #pragma unroll
    for (int m = 0; m < Lc; ++m) a[m] *= inv;

    // out[d] = sum_j a[j] * x_j[d]  (x values still live in VGPRs)
    float4 o = make_float4(0.f, 0.f, 0.f, 0.f);
    #pragma unroll
    for (int j = 0; j < Lc; ++j) {
        o.x = fmaf(a[j], v[j].x, o.x);
        o.y = fmaf(a[j], v[j].y, o.y);
        o.z = fmaf(a[j], v[j].z, o.z);
        o.w = fmaf(a[j], v[j].w, o.w);
    }
    *(float4*)(out + base) = o;
}

extern "C" void kernel_launch(void* const* d_in, const int* in_sizes, int n_in,
                              void* d_out, int out_size, void* d_ws, size_t ws_size,
                              hipStream_t stream) {
    const float* x0 = (const float*)d_in[0];
    const float* x1 = (const float*)d_in[1];
    const float* x2 = (const float*)d_in[2];
    const float* x3 = (const float*)d_in[3];
    const float* x4 = (const float*)d_in[4];
    const float* x5 = (const float*)d_in[5];
    const float* Ws = (const float*)d_in[6];
    float* out = (float*)d_out;

    const int positions = Bc * Sc;            // 32768
    const int blocks = positions / 2;         // 2 positions (4 waves) per block
    densely_att_kernel<<<blocks, 256, 0, stream>>>(x0, x1, x2, x3, x4, x5, Ws, out);
}